// Round 3
// baseline (133.171 us; speedup 1.0000x reference)
//
#include <hip/hip_runtime.h>

// Problem constants: T=1024, B=256, H=20
#define T_N 1024
#define B_N 256
#define H_N 20
#define NW  8            // waves per block
#define NDW (NW - 1)     // dot waves
#define SIH 1096         // I-history row stride in HALVES (conflict-free layout, see R5)

typedef _Float16 h8_t __attribute__((ext_vector_type(8)));

#if __has_builtin(__builtin_amdgcn_fdot2)
#define DOT8(acc, mv, iv)                                                           \
    acc = __builtin_amdgcn_fdot2(__builtin_shufflevector(mv, mv, 0, 1),             \
                                 __builtin_shufflevector(iv, iv, 0, 1), acc, false);\
    acc = __builtin_amdgcn_fdot2(__builtin_shufflevector(mv, mv, 2, 3),             \
                                 __builtin_shufflevector(iv, iv, 2, 3), acc, false);\
    acc = __builtin_amdgcn_fdot2(__builtin_shufflevector(mv, mv, 4, 5),             \
                                 __builtin_shufflevector(iv, iv, 4, 5), acc, false);\
    acc = __builtin_amdgcn_fdot2(__builtin_shufflevector(mv, mv, 6, 7),             \
                                 __builtin_shufflevector(iv, iv, 6, 7), acc, false);
#else
#define DOT8(acc, mv, iv)                                                           \
    _Pragma("unroll")                                                               \
    for (int _k = 0; _k < 8; ++_k) acc = fmaf((float)mv[_k], (float)iv[_k], acc);
#endif

__device__ __forceinline__ float rdlane_i(float v, int lane) {
    return __uint_as_float((unsigned)__builtin_amdgcn_readlane((int)__float_as_uint(v), lane));
}
__device__ __forceinline__ float fast_tanh(float x) {
    const float e = __expf(2.0f * x);
    return fmaf(-2.0f, __builtin_amdgcn_rcpf(e + 1.0f), 1.0f);
}
__device__ __forceinline__ float fast_sigmoid(float x) {
    return __builtin_amdgcn_rcpf(1.0f + __expf(-x));
}

// explicit literal-token repetition (tokens must be plain literals for ##)
#define REP64(F) \
    F(0) F(1) F(2) F(3) F(4) F(5) F(6) F(7) F(8) F(9) F(10) F(11) F(12) F(13) \
    F(14) F(15) F(16) F(17) F(18) F(19) F(20) F(21) F(22) F(23) F(24) F(25)   \
    F(26) F(27) F(28) F(29) F(30) F(31) F(32) F(33) F(34) F(35) F(36) F(37)   \
    F(38) F(39) F(40) F(41) F(42) F(43) F(44) F(45) F(46) F(47) F(48) F(49)   \
    F(50) F(51) F(52) F(53) F(54) F(55) F(56) F(57) F(58) F(59) F(60) F(61)   \
    F(62) F(63)

// ---------------------------------------------------------------------------
// R3: TWO batch elements per block (grid 128). Rationale from R0-R2 counters:
// VALUBusy*time ~= static op count -> wave0's serial chain stalls ~70% on
// dependent-VALU latency (one in-order wave can't fill its own bubbles).
// Interleaving two INDEPENDENT chains in program order fills them. Also:
// shorter step algebra (11 ops/chain, 2-op recurrence cycle) with dt^2
// folded into the rm/rn tables, meT1 and the P-merge.
//   I' = I * fma(dtb, S, c1)            c1 = 1 - dt*gamma
//   S' = fma(fma(-dtb, I, 1), S, sum')  sum' = dt^2-scaled integral
// me-tables are SHARED between the two chains; dot waves share the mv
// operand (3 b128 loads per segment pair instead of 4).
// ---------------------------------------------------------------------------
__global__ __launch_bounds__(512, 1) void scan_kernel(
    const float* __restrict__ t,
    const float* __restrict__ y,
    const float* __restrict__ w1, const float* __restrict__ b1,
    const float* __restrict__ w2, const float* __restrict__ b2,
    const float* __restrict__ w3, const float* __restrict__ b3,
    const float* __restrict__ w4, const float* __restrict__ b4,
    const float* __restrict__ beta_p,
    const float* __restrict__ gamma_p,
    float* __restrict__ out)     // [solution (T*B*3) | diff (T*B*3)]
{
    __shared__ __align__(16) float    sMeF[T_N];       // fp32 me
    __shared__ __align__(16) _Float16 sMeH[T_N];       // fp16 me (dot operand A)
    __shared__ __align__(16) _Float16 sIhR0[8 * SIH];  // batch-0 I-history rows
    __shared__ __align__(16) _Float16 sIhR1[8 * SIH];  // batch-1 I-history rows
    __shared__ float P[2][2][NDW][64];                 // [parity][batch][wave][lane]

    const int b0  = blockIdx.x * 2;
    const int b1i = b0 + 1;
    const int tid = threadIdx.x;
    const int wid = tid >> 6;
    const int L   = tid & 63;

    // per-lane dot-geometry constants (chunk-invariant)
    const int f    = (-L) & 7;            // misalignment of lane L's me window
    const int R8   = L + f;               // L rounded up to multiple of 8
    const int row  = L & 7;               // I-history row for this lane
    const int iofs = row * SIH + (f ? 0 : 8);

    // zero the row front-pads (slots representing I[<0])
    if (tid < 64) {
        sIhR0[(tid >> 3) * SIH + (tid & 7)] = (_Float16)0.0f;
        sIhR1[(tid >> 3) * SIH + (tid & 7)] = (_Float16)0.0f;
    }

    // ---- Phase A: me MLP (2 values/thread) ----
#pragma unroll
    for (int v = 0; v < 2; ++v) {
        const int mi = tid + v * 512;
        const float x = t[mi];

        float h1[H_N], h2[H_N];
#pragma unroll
        for (int k = 0; k < H_N; ++k) h1[k] = fast_tanh(fmaf(x, w1[k], b1[k]));

#pragma unroll 4
        for (int k = 0; k < H_N; ++k) {
            float a = b2[k];
#pragma unroll
            for (int j = 0; j < H_N; ++j) a = fmaf(h1[j], w2[j * H_N + k], a);
            h2[k] = fast_tanh(a);
        }

        float a4 = b4[0];
#pragma unroll 4
        for (int k = 0; k < H_N; ++k) {
            float a = b3[k];
#pragma unroll
            for (int j = 0; j < H_N; ++j) a = fmaf(h2[j], w3[j * H_N + k], a);
            a4 = fmaf(fast_tanh(a), w4[k], a4);
        }

        const float meval = fast_sigmoid(a4);
        sMeF[mi] = meval;
        sMeH[mi] = (_Float16)meval;
    }

    // ---- scalars / state ----
    const float dt    = t[0] - t[1];
    const float beta  = beta_p[0];
    const float gma   = gamma_p[0];
    const float invdt = 1.0f / dt;
    const float dt2   = dt * dt;

    const float S00 = y[b0 * 3 + 0];
    const float I00 = y[b0 * 3 + 1];
    const float R00 = y[b0 * 3 + 2];
    const float TOT0 = S00 + I00 + R00;

    const float S10 = y[b1i * 3 + 0];
    const float I10 = y[b1i * 3 + 1];
    const float R10 = y[b1i * 3 + 2];
    const float TOT1 = S10 + I10 + R10;

    // publish I[0] into all 8 rows of both history arrays
    if (tid < 8) {
        sIhR0[tid * SIH + 8 - tid] = (_Float16)I00;
        sIhR1[tid * SIH + 8 - tid] = (_Float16)I10;
    }

    float* __restrict__ diff = out + (size_t)T_N * B_N * 3;
    if (tid < 6) {
        const int bb = (tid >= 3) ? b1i : b0;
        diff[((size_t)(T_N - 1) * B_N + bb) * 3 + (tid % 3)] = 0.0f;
    }

    __syncthreads();   // sMeF/sMeH/pads/I0 visible

    // fixup me weights (chunk-invariant, UNSCALED — applied to raw P sums)
    float mf[7];
#pragma unroll
    for (int d = 1; d <= 7; ++d) mf[d - 1] = sMeF[T_N - 64 - L - d];

    const float dtb   = dt * beta;
    const float ndtb  = -dtb;
    const float c1    = fmaf(-dt, gma, 1.0f);     // 1 - dt*gamma
    const float meT1s = dt2 * sMeF[T_N - 1];      // dt^2-scaled me[T-1]

    float S0v = S00, I0v = I00, oS0 = S00, oI0 = I00;
    float S1v = S10, I1v = I10, oS1 = S10, oI1 = I10;
    float acc_cur0 = 0.0f, acc_nxt0 = 0.0f, pre0 = 0.0f;
    float acc_cur1 = 0.0f, acc_nxt1 = 0.0f, pre1 = 0.0f;
    float carryS0 = S00, carryI0 = I00;
    float carryS1 = S10, carryI1 = I10;

    // register me-tables (shared by both chains), dt^2-scaled
#define TBLDECL(k) float rm_##k, rn_##k;
    REP64(TBLDECL)
#undef TBLDECL
    if (wid == 0) {
#define TBLINIT(k)                                                          \
        rm_##k = (((k) < L) ? sMeF[T_N - L + (k)] : 0.0f) * dt2;            \
        rn_##k = dt2 * sMeF[T_N - 64 - L + (k)];
        REP64(TBLINIT)
#undef TBLINIT
#define TBLPIN(k) asm volatile("" : "+v"(rm_##k), "+v"(rn_##k));
        REP64(TBLPIN)
#undef TBLPIN
    }

    // serial step M_ for BOTH chains. Entering (S,I) = y_{64c+M_-1}.
    // sum uses pre-step I (I_{j-1}) for the d=1 term (meT1s patch).
    // Recurrence cycle per chain: 2 dependent ops (a->I' ; b->S').
#define STEPB(M_, FIRST_)                                               \
    {                                                                   \
        const float sum0 = (FIRST_) ? pre0 : fmaf(meT1s, I0v, pre0);    \
        const float sum1 = (FIRST_) ? pre1 : fmaf(meT1s, I1v, pre1);    \
        float pnx0 = pre0, pnx1 = pre1;                                 \
        if ((M_) < 63) {                                                \
            pnx0 = rdlane_i(acc_cur0, (M_) + 1);                        \
            pnx1 = rdlane_i(acc_cur1, (M_) + 1);                        \
        }                                                               \
        const float a0 = fmaf(dtb, S0v, c1);                            \
        const float a1 = fmaf(dtb, S1v, c1);                            \
        const float bb0 = fmaf(ndtb, I0v, 1.0f);                        \
        const float bb1 = fmaf(ndtb, I1v, 1.0f);                        \
        S0v = fmaf(bb0, S0v, sum0);                                     \
        S1v = fmaf(bb1, S1v, sum1);                                     \
        I0v = I0v * a0;                                                 \
        I1v = I1v * a1;                                                 \
        const bool cap = (L == (M_));                                   \
        oS0 = cap ? S0v : oS0;                                          \
        oI0 = cap ? I0v : oI0;                                          \
        oS1 = cap ? S1v : oS1;                                          \
        oI1 = cap ? I1v : oI1;                                          \
        acc_cur0 = fmaf(rm_##M_, I0v, acc_cur0);                        \
        acc_nxt0 = fmaf(rn_##M_, I0v, acc_nxt0);                        \
        acc_cur1 = fmaf(rm_##M_, I1v, acc_cur1);                        \
        acc_nxt1 = fmaf(rn_##M_, I1v, acc_nxt1);                        \
        pre0 = pnx0;                                                    \
        pre1 = pnx1;                                                    \
    }
#define STEP_GE1(M_) if ((M_) >= 1) STEPB(M_, false)
#define STEP_GE2(M_) if ((M_) >= 2) STEPB(M_, false)

    for (int c = 0; c < 16; ++c) {
        if (wid == 0) {
            if (c == 0) {
                // fold initial I0 (t=0 term); lane0's rm_0 is the 0 pad
                acc_cur0 = rm_0 * I0v;  acc_nxt0 = rn_0 * I0v;
                acc_cur1 = rm_0 * I1v;  acc_nxt1 = rn_0 * I1v;
                pre0 = rdlane_i(acc_cur0, 1);
                pre1 = rdlane_i(acc_cur1, 1);
                STEPB(1, true)
                REP64(STEP_GE2)
            } else {
                float ps0 = 0.0f, ps1 = 0.0f;
#pragma unroll
                for (int w = 0; w < NDW; ++w) {
                    ps0 += P[c & 1][0][w][L];
                    ps1 += P[c & 1][1][w][L];
                }
                acc_cur0 = fmaf(dt2, ps0, acc_nxt0);   // scale raw P sums
                acc_cur1 = fmaf(dt2, ps1, acc_nxt1);
                acc_nxt0 = 0.0f;
                acc_nxt1 = 0.0f;
                pre0 = rdlane_i(acc_cur0, 0);
                pre1 = rdlane_i(acc_cur1, 0);
                STEPB(0, true)
                REP64(STEP_GE1)
            }

            // ---- chunk epilogue (wave 0), both batches ----
            const int j = 64 * c + L;
            const _Float16 hI0 = (_Float16)oI0;
            const _Float16 hI1 = (_Float16)oI1;
#pragma unroll
            for (int r = 0; r < 8; ++r) sIhR0[r * SIH + 8 + (j - r)] = hI0;
#pragma unroll
            for (int r = 0; r < 8; ++r) sIhR1[r * SIH + 8 + (j - r)] = hI1;

            const float oR0 = TOT0 - oS0 - oI0;
            const float oR1 = TOT1 - oS1 - oI1;
            const size_t so0 = ((size_t)j * B_N + b0) * 3;
            out[so0 + 0] = oS0;
            out[so0 + 1] = oI0;
            out[so0 + 2] = oR0;
            out[so0 + 3] = oS1;    // batch b0+1 is contiguous: (j*B_N+b1)*3 = so0+3
            out[so0 + 4] = oI1;
            out[so0 + 5] = oR1;

            float sm10 = __shfl_up(oS0, 1);
            float im10 = __shfl_up(oI0, 1);
            float sm11 = __shfl_up(oS1, 1);
            float im11 = __shfl_up(oI1, 1);
            if (L == 0) { sm10 = carryS0; im10 = carryI0; sm11 = carryS1; im11 = carryI1; }
            if (j > 0) {
                const float d00 = (oS0 - sm10) * invdt;
                const float d01 = (oI0 - im10) * invdt;
                const float d10 = (oS1 - sm11) * invdt;
                const float d11 = (oI1 - im11) * invdt;
                const size_t dofs = ((size_t)(j - 1) * B_N + b0) * 3;
                diff[dofs + 0] = d00;
                diff[dofs + 1] = d01;
                diff[dofs + 2] = -d00 - d01;
                diff[dofs + 3] = d10;
                diff[dofs + 4] = d11;
                diff[dofs + 5] = -d10 - d11;
            }
            carryS0 = rdlane_i(oS0, 63);
            carryI0 = rdlane_i(oI0, 63);
            carryS1 = rdlane_i(oS1, 63);
            carryI1 = rdlane_i(oI1, 63);
        } else if (c < 15) {
            // history dots for chunk c+1 over tau < 64c, both batches.
            // mv (me window) is shared; 3 b128 loads per segment instead of 4.
            const int w    = wid - 1;
            const int G    = 8 * c;
            const int idx0 = (T_N - 64 * (c + 1)) - R8;
            float p00 = 0.0f, p01 = 0.0f;   // batch 0, two pipelines
            float p10 = 0.0f, p11 = 0.0f;   // batch 1, two pipelines
            int s = w;
            for (; s + NDW < G; s += 2 * NDW) {
                const h8_t mv0  = *(const h8_t*)&sMeH[idx0 + 8 * s];
                const h8_t mv1  = *(const h8_t*)&sMeH[idx0 + 8 * (s + NDW)];
                const h8_t iva0 = *(const h8_t*)&sIhR0[iofs + 8 * s];
                const h8_t iva1 = *(const h8_t*)&sIhR0[iofs + 8 * (s + NDW)];
                const h8_t ivb0 = *(const h8_t*)&sIhR1[iofs + 8 * s];
                const h8_t ivb1 = *(const h8_t*)&sIhR1[iofs + 8 * (s + NDW)];
                DOT8(p00, mv0, iva0)
                DOT8(p01, mv1, iva1)
                DOT8(p10, mv0, ivb0)
                DOT8(p11, mv1, ivb1)
            }
            if (s < G) {
                const h8_t mv0  = *(const h8_t*)&sMeH[idx0 + 8 * s];
                const h8_t iva0 = *(const h8_t*)&sIhR0[iofs + 8 * s];
                const h8_t ivb0 = *(const h8_t*)&sIhR1[iofs + 8 * s];
                DOT8(p00, mv0, iva0)
                DOT8(p10, mv0, ivb0)
            }
            float p0 = p00 + p01;
            float p1 = p10 + p11;
            if (w == 0) {
                // tail fixup: tau = 64c - d, d = 1..f
#pragma unroll
                for (int d = 1; d <= 7; ++d) {
                    const float ih0 = (float)sIhR0[8 + 64 * c - d];   // row 0
                    const float ih1 = (float)sIhR1[8 + 64 * c - d];
                    if (d <= f) {
                        p0 = fmaf(mf[d - 1], ih0, p0);
                        p1 = fmaf(mf[d - 1], ih1, p1);
                    }
                }
            }
            P[(c + 1) & 1][0][w][L] = p0;
            P[(c + 1) & 1][1][w][L] = p1;
        }
        __syncthreads();
    }
#undef STEPB
#undef STEP_GE1
#undef STEP_GE2
}

// ---------------------------------------------------------------------------
// Launcher: 128 blocks, 2 batch elements each
// ---------------------------------------------------------------------------
extern "C" void kernel_launch(void* const* d_in, const int* in_sizes, int n_in,
                              void* d_out, int out_size, void* d_ws, size_t ws_size,
                              hipStream_t stream) {
    const float* t     = (const float*)d_in[0];
    const float* y     = (const float*)d_in[1];
    const float* w1    = (const float*)d_in[2];
    const float* b1    = (const float*)d_in[3];
    const float* w2    = (const float*)d_in[4];
    const float* b2    = (const float*)d_in[5];
    const float* w3    = (const float*)d_in[6];
    const float* b3    = (const float*)d_in[7];
    const float* w4    = (const float*)d_in[8];
    const float* b4    = (const float*)d_in[9];
    const float* beta  = (const float*)d_in[10];
    const float* gamma = (const float*)d_in[11];

    scan_kernel<<<B_N / 2, 512, 0, stream>>>(t, y, w1, b1, w2, b2, w3, b3, w4, b4,
                                             beta, gamma, (float*)d_out);
}

// Round 4
// 122.606 us; speedup vs baseline: 1.0862x; 1.0862x over previous
//
#include <hip/hip_runtime.h>

// Problem constants: T=1024, B=256, H=20
#define T_N 1024
#define B_N 256
#define H_N 20
#define NW  8            // waves per block
#define NDW (NW - 1)     // dot waves
#define SIH 1096         // I-history row stride in HALVES (conflict-free layout, see R5)

typedef _Float16 h8_t __attribute__((ext_vector_type(8)));

#if __has_builtin(__builtin_amdgcn_fdot2)
#define DOT8(acc, mv, iv)                                                           \
    acc = __builtin_amdgcn_fdot2(__builtin_shufflevector(mv, mv, 0, 1),             \
                                 __builtin_shufflevector(iv, iv, 0, 1), acc, false);\
    acc = __builtin_amdgcn_fdot2(__builtin_shufflevector(mv, mv, 2, 3),             \
                                 __builtin_shufflevector(iv, iv, 2, 3), acc, false);\
    acc = __builtin_amdgcn_fdot2(__builtin_shufflevector(mv, mv, 4, 5),             \
                                 __builtin_shufflevector(iv, iv, 4, 5), acc, false);\
    acc = __builtin_amdgcn_fdot2(__builtin_shufflevector(mv, mv, 6, 7),             \
                                 __builtin_shufflevector(iv, iv, 6, 7), acc, false);
#else
#define DOT8(acc, mv, iv)                                                           \
    _Pragma("unroll")                                                               \
    for (int _k = 0; _k < 8; ++_k) acc = fmaf((float)mv[_k], (float)iv[_k], acc);
#endif

__device__ __forceinline__ float rdlane_i(float v, int lane) {
    return __uint_as_float((unsigned)__builtin_amdgcn_readlane((int)__float_as_uint(v), lane));
}
__device__ __forceinline__ float fast_tanh(float x) {
    const float e = __expf(2.0f * x);
    return fmaf(-2.0f, __builtin_amdgcn_rcpf(e + 1.0f), 1.0f);
}
__device__ __forceinline__ float fast_sigmoid(float x) {
    return __builtin_amdgcn_rcpf(1.0f + __expf(-x));
}

// explicit literal-token repetition (tokens must be plain literals for ##)
#define REP64(F) \
    F(0) F(1) F(2) F(3) F(4) F(5) F(6) F(7) F(8) F(9) F(10) F(11) F(12) F(13) \
    F(14) F(15) F(16) F(17) F(18) F(19) F(20) F(21) F(22) F(23) F(24) F(25)   \
    F(26) F(27) F(28) F(29) F(30) F(31) F(32) F(33) F(34) F(35) F(36) F(37)   \
    F(38) F(39) F(40) F(41) F(42) F(43) F(44) F(45) F(46) F(47) F(48) F(49)   \
    F(50) F(51) F(52) F(53) F(54) F(55) F(56) F(57) F(58) F(59) F(60) F(61)   \
    F(62) F(63)

// ---------------------------------------------------------------------------
// R4: grid 256 (R3 proved wall time = per-block critical path), single batch
// per block, with the serial step restructured so the v_readlane broadcast is
// DISTANCE-2 pipelined:
//   at step M read lane (M+2)'s accumulator (missing folds M, M+1);
//   at step M+2 patch with dt^2*(me[T-1]*I_{j-1} + me[T-2]*I_{j-2}).
// This takes the readlane (VALU->SGPR->VALU hazard) off the loop-carried
// cycle (R3's cost model: ~80cy/step fixed stall shared across chains =
// the fold->readlane->sum->S->a->I cycle). Remaining loop-carried cycle is
// the pure SIR recurrence (~2 dependent fmas/step). Also keeps R3's step
// algebra: dt^2 folded into rm/rn tables, meT1s/meT2s, and the P-merge:
//   I' = I * fma(dtb, S, c1),  S' = fma(fma(-dtb, I, 1), S, sum)
// ---------------------------------------------------------------------------
__global__ __launch_bounds__(512, 1) void scan_kernel(
    const float* __restrict__ t,
    const float* __restrict__ y,
    const float* __restrict__ w1, const float* __restrict__ b1,
    const float* __restrict__ w2, const float* __restrict__ b2,
    const float* __restrict__ w3, const float* __restrict__ b3,
    const float* __restrict__ w4, const float* __restrict__ b4,
    const float* __restrict__ beta_p,
    const float* __restrict__ gamma_p,
    float* __restrict__ out)     // [solution (T*B*3) | diff (T*B*3)]
{
    __shared__ __align__(16) float    sMeF[T_N];      // fp32 me
    __shared__ __align__(16) _Float16 sMeH[T_N];      // fp16 me (dot operand A)
    __shared__ __align__(16) _Float16 sIhR[8 * SIH];  // 8 shifted fp16 I-history rows
    __shared__ float P[2][NDW][64];

    const int b   = blockIdx.x;
    const int tid = threadIdx.x;
    const int wid = tid >> 6;
    const int L   = tid & 63;

    // per-lane dot-geometry constants (chunk-invariant)
    const int f    = (-L) & 7;            // misalignment of lane L's me window
    const int R8   = L + f;               // L rounded up to multiple of 8
    const int row  = L & 7;               // I-history row for this lane
    const int iofs = row * SIH + (f ? 0 : 8);

    // zero the row front-pads (slots representing I[<0])
    if (tid < 64) sIhR[(tid >> 3) * SIH + (tid & 7)] = (_Float16)0.0f;

    // ---- Phase A: me MLP (2 values/thread) ----
#pragma unroll
    for (int v = 0; v < 2; ++v) {
        const int mi = tid + v * 512;
        const float x = t[mi];

        float h1[H_N], h2[H_N];
#pragma unroll
        for (int k = 0; k < H_N; ++k) h1[k] = fast_tanh(fmaf(x, w1[k], b1[k]));

#pragma unroll 4
        for (int k = 0; k < H_N; ++k) {
            float a = b2[k];
#pragma unroll
            for (int j = 0; j < H_N; ++j) a = fmaf(h1[j], w2[j * H_N + k], a);
            h2[k] = fast_tanh(a);
        }

        float a4 = b4[0];
#pragma unroll 4
        for (int k = 0; k < H_N; ++k) {
            float a = b3[k];
#pragma unroll
            for (int j = 0; j < H_N; ++j) a = fmaf(h2[j], w3[j * H_N + k], a);
            a4 = fmaf(fast_tanh(a), w4[k], a4);
        }

        const float meval = fast_sigmoid(a4);
        sMeF[mi] = meval;
        sMeH[mi] = (_Float16)meval;
    }

    // ---- scalars / state ----
    const float dt    = t[0] - t[1];
    const float beta  = beta_p[0];
    const float gma   = gamma_p[0];
    const float invdt = 1.0f / dt;
    const float dt2   = dt * dt;

    const float S0 = y[b * 3 + 0];
    const float I0 = y[b * 3 + 1];
    const float R0 = y[b * 3 + 2];
    const float TOT = S0 + I0 + R0;     // SIR total conserved

    // publish I[0] into all 8 rows
    if (tid < 8) sIhR[tid * SIH + 8 - tid] = (_Float16)I0;

    float* __restrict__ diff = out + (size_t)T_N * B_N * 3;
    if (tid < 3) diff[((size_t)(T_N - 1) * B_N + b) * 3 + tid] = 0.0f;

    __syncthreads();   // sMeF/sMeH/pads/I0 visible

    // fixup me weights (chunk-invariant, UNSCALED — applied to raw P sums)
    float mf[7];
#pragma unroll
    for (int d = 1; d <= 7; ++d) mf[d - 1] = sMeF[T_N - 64 - L - d];

    const float dtb   = dt * beta;
    const float ndtb  = -dtb;
    const float c1    = fmaf(-dt, gma, 1.0f);     // 1 - dt*gamma
    const float meT1s = dt2 * sMeF[T_N - 1];      // dt^2 * me[T-1]
    const float meT2s = dt2 * sMeF[T_N - 2];      // dt^2 * me[T-2]

    float S = S0, I = I0, Iprev = 0.0f, oS = S0, oI = I0;
    float acc_cur = 0.0f, acc_nxt = 0.0f;
    float pre_cur = 0.0f, pre_nxt = 0.0f;
    float carryS = S0, carryI = I0;

    // register me-tables (dt^2-scaled): 128 NAMED scalars
#define TBLDECL(k) float rm_##k, rn_##k;
    REP64(TBLDECL)
#undef TBLDECL
    if (wid == 0) {
#define TBLINIT(k)                                                          \
        rm_##k = (((k) < L) ? sMeF[T_N - L + (k)] : 0.0f) * dt2;            \
        rn_##k = dt2 * sMeF[T_N - 64 - L + (k)];
        REP64(TBLINIT)
#undef TBLINIT
#define TBLPIN(k) asm volatile("" : "+v"(rm_##k), "+v"(rn_##k));
        REP64(TBLPIN)
#undef TBLPIN
    }

    // Distance-2 pipelined step. Entering: S,I = y_{j-1}, Iprev = I_{j-2},
    // pre_cur = lane-(M)'s acc base read 2 steps ago, pre_nxt = lane-(M+1)'s.
    // NP_ = number of recent-term patches this step needs (0/1/2).
#define STEPC(M_, NP_)                                                  \
    {                                                                   \
        float sum;                                                      \
        if ((NP_) == 0)      sum = pre_cur;                             \
        else if ((NP_) == 1) sum = fmaf(meT1s, I, pre_cur);             \
        else                 sum = fmaf(meT1s, I, fmaf(meT2s, Iprev, pre_cur)); \
        float rdv = pre_nxt;                                            \
        if ((M_) + 2 <= 63) rdv = rdlane_i(acc_cur, (M_) + 2);          \
        const float a  = fmaf(dtb, S, c1);                              \
        const float bb = fmaf(ndtb, I, 1.0f);                           \
        const float Sn = fmaf(bb, S, sum);                              \
        const float In = I * a;                                         \
        const bool cap = (L == (M_));                                   \
        oS = cap ? Sn : oS;                                             \
        oI = cap ? In : oI;                                             \
        acc_cur = fmaf(rm_##M_, In, acc_cur);                           \
        acc_nxt = fmaf(rn_##M_, In, acc_nxt);                           \
        Iprev = I;                                                      \
        I = In;                                                         \
        S = Sn;                                                         \
        pre_cur = pre_nxt;                                              \
        pre_nxt = rdv;                                                  \
    }
#define STEP_GE2(M_) if ((M_) >= 2) STEPC(M_, 2)
#define STEP_GE3(M_) if ((M_) >= 3) STEPC(M_, 2)

    for (int c = 0; c < 16; ++c) {
        if (wid == 0) {
            if (c == 0) {
                // fold initial I0 (tau=0 term); lane0's rm_0 is the 0 pad
                acc_cur = rm_0 * I;
                acc_nxt = rn_0 * I;
                pre_cur = rdlane_i(acc_cur, 1);   // step 1: complete
                pre_nxt = rdlane_i(acc_cur, 2);   // step 2: misses fold 1
                STEPC(1, 0)                        // reads lane 3
                STEPC(2, 1)                        // reads lane 4
                REP64(STEP_GE3)
            } else {
                float ps = 0.0f;
#pragma unroll
                for (int w = 0; w < NDW; ++w) ps += P[c & 1][w][L];
                acc_cur = fmaf(dt2, ps, acc_nxt);  // scale raw P sums
                acc_nxt = 0.0f;
                pre_cur = rdlane_i(acc_cur, 0);    // step 0: complete
                pre_nxt = rdlane_i(acc_cur, 1);    // step 1: misses fold 0
                STEPC(0, 0)                         // reads lane 2
                STEPC(1, 1)                         // reads lane 3
                REP64(STEP_GE2)
            }

            // ---- chunk epilogue (wave 0) ----
            const int j = 64 * c + L;
            const _Float16 hI = (_Float16)oI;
#pragma unroll
            for (int r = 0; r < 8; ++r) sIhR[r * SIH + 8 + (j - r)] = hI;

            const float oR = TOT - oS - oI;
            const size_t so = ((size_t)j * B_N + b) * 3;
            out[so + 0] = oS;
            out[so + 1] = oI;
            out[so + 2] = oR;

            float sm1 = __shfl_up(oS, 1);
            float im1 = __shfl_up(oI, 1);
            if (L == 0) { sm1 = carryS; im1 = carryI; }
            if (j > 0) {
                const float d0 = (oS - sm1) * invdt;
                const float d1 = (oI - im1) * invdt;
                const float d2 = -d0 - d1;
                const size_t dofs = ((size_t)(j - 1) * B_N + b) * 3;
                diff[dofs + 0] = d0;
                diff[dofs + 1] = d1;
                diff[dofs + 2] = d2;
            }
            carryS = rdlane_i(oS, 63);
            carryI = rdlane_i(oI, 63);
        } else if (c < 15) {
            // history dot for chunk c+1 over tau < 64c (R5 layout, unchanged)
            const int w    = wid - 1;
            const int G    = 8 * c;
            const int idx0 = (T_N - 64 * (c + 1)) - R8;
            float p0 = 0.0f, p1 = 0.0f;
            int s = w;
            for (; s + NDW < G; s += 2 * NDW) {
                const h8_t mv0 = *(const h8_t*)&sMeH[idx0 + 8 * s];
                const h8_t iv0 = *(const h8_t*)&sIhR[iofs + 8 * s];
                const h8_t mv1 = *(const h8_t*)&sMeH[idx0 + 8 * (s + NDW)];
                const h8_t iv1 = *(const h8_t*)&sIhR[iofs + 8 * (s + NDW)];
                DOT8(p0, mv0, iv0)
                DOT8(p1, mv1, iv1)
            }
            if (s < G) {
                const h8_t mv0 = *(const h8_t*)&sMeH[idx0 + 8 * s];
                const h8_t iv0 = *(const h8_t*)&sIhR[iofs + 8 * s];
                DOT8(p0, mv0, iv0)
            }
            float p = p0 + p1;
            if (w == 0) {
                // tail fixup: tau = 64c - d, d = 1..f (raw, scaled at merge)
#pragma unroll
                for (int d = 1; d <= 7; ++d) {
                    const float ih = (float)sIhR[8 + 64 * c - d];   // row 0
                    if (d <= f) p = fmaf(mf[d - 1], ih, p);
                }
            }
            P[(c + 1) & 1][w][L] = p;
        }
        __syncthreads();
    }
#undef STEPC
#undef STEP_GE2
#undef STEP_GE3
}

// ---------------------------------------------------------------------------
// Launcher
// ---------------------------------------------------------------------------
extern "C" void kernel_launch(void* const* d_in, const int* in_sizes, int n_in,
                              void* d_out, int out_size, void* d_ws, size_t ws_size,
                              hipStream_t stream) {
    const float* t     = (const float*)d_in[0];
    const float* y     = (const float*)d_in[1];
    const float* w1    = (const float*)d_in[2];
    const float* b1    = (const float*)d_in[3];
    const float* w2    = (const float*)d_in[4];
    const float* b2    = (const float*)d_in[5];
    const float* w3    = (const float*)d_in[6];
    const float* b3    = (const float*)d_in[7];
    const float* w4    = (const float*)d_in[8];
    const float* b4    = (const float*)d_in[9];
    const float* beta  = (const float*)d_in[10];
    const float* gamma = (const float*)d_in[11];

    scan_kernel<<<B_N, 512, 0, stream>>>(t, y, w1, b1, w2, b2, w3, b3, w4, b4,
                                         beta, gamma, (float*)d_out);
}

// Round 5
// 119.334 us; speedup vs baseline: 1.1160x; 1.0274x over previous
//
#include <hip/hip_runtime.h>

// Problem constants: T=1024, B=256, H=20
#define T_N 1024
#define B_N 256
#define H_N 20
#define NW  8            // waves per block
#define NDW (NW - 1)     // dot waves
#define SIH 1096         // I-history row stride in HALVES (conflict-free layout, see R5)

typedef _Float16 h8_t __attribute__((ext_vector_type(8)));

#if __has_builtin(__builtin_amdgcn_fdot2)
#define DOT8(acc, mv, iv)                                                           \
    acc = __builtin_amdgcn_fdot2(__builtin_shufflevector(mv, mv, 0, 1),             \
                                 __builtin_shufflevector(iv, iv, 0, 1), acc, false);\
    acc = __builtin_amdgcn_fdot2(__builtin_shufflevector(mv, mv, 2, 3),             \
                                 __builtin_shufflevector(iv, iv, 2, 3), acc, false);\
    acc = __builtin_amdgcn_fdot2(__builtin_shufflevector(mv, mv, 4, 5),             \
                                 __builtin_shufflevector(iv, iv, 4, 5), acc, false);\
    acc = __builtin_amdgcn_fdot2(__builtin_shufflevector(mv, mv, 6, 7),             \
                                 __builtin_shufflevector(iv, iv, 6, 7), acc, false);
#else
#define DOT8(acc, mv, iv)                                                           \
    _Pragma("unroll")                                                               \
    for (int _k = 0; _k < 8; ++_k) acc = fmaf((float)mv[_k], (float)iv[_k], acc);
#endif

__device__ __forceinline__ float rdlane_i(float v, int lane) {
    return __uint_as_float((unsigned)__builtin_amdgcn_readlane((int)__float_as_uint(v), lane));
}
__device__ __forceinline__ float fast_tanh(float x) {
    const float e = __expf(2.0f * x);
    return fmaf(-2.0f, __builtin_amdgcn_rcpf(e + 1.0f), 1.0f);
}
__device__ __forceinline__ float fast_sigmoid(float x) {
    return __builtin_amdgcn_rcpf(1.0f + __expf(-x));
}

// explicit literal-token repetition (tokens must be plain literals for ##)
#define REP64(F) \
    F(0) F(1) F(2) F(3) F(4) F(5) F(6) F(7) F(8) F(9) F(10) F(11) F(12) F(13) \
    F(14) F(15) F(16) F(17) F(18) F(19) F(20) F(21) F(22) F(23) F(24) F(25)   \
    F(26) F(27) F(28) F(29) F(30) F(31) F(32) F(33) F(34) F(35) F(36) F(37)   \
    F(38) F(39) F(40) F(41) F(42) F(43) F(44) F(45) F(46) F(47) F(48) F(49)   \
    F(50) F(51) F(52) F(53) F(54) F(55) F(56) F(57) F(58) F(59) F(60) F(61)   \
    F(62) F(63)

// ---------------------------------------------------------------------------
// R5: three critical-path attacks on wave0 (R1/R2/R4 all null -> fixed
// ~75cy/step cost is arbitration or chunk-head serialization):
//  1. s_setprio(3) on wave0 for Phase B (T5: role-split waves; the dot wave
//     sharing wave0's SIMD steals issue slots via round-robin arbitration).
//  2. P transposed to [parity][lane][8]: chunk-head merge = 2x ds_read_b128
//     + 7 adds instead of 7 serial ds_read_b32 (serial-head trim).
//  3. distance-1 readlane broadcast (R4's distance-2 proved readlane latency
//     is not on the critical path; save 1 fma/step).
// Algebra (R3/R4, verified): dt^2 folded into rm/rn tables, meT1s, P-merge.
//   I' = I * fma(dtb, S, c1),  S' = fma(fma(-dtb, I, 1), S, sum)
// ---------------------------------------------------------------------------
__global__ __launch_bounds__(512, 1) void scan_kernel(
    const float* __restrict__ t,
    const float* __restrict__ y,
    const float* __restrict__ w1, const float* __restrict__ b1,
    const float* __restrict__ w2, const float* __restrict__ b2,
    const float* __restrict__ w3, const float* __restrict__ b3,
    const float* __restrict__ w4, const float* __restrict__ b4,
    const float* __restrict__ beta_p,
    const float* __restrict__ gamma_p,
    float* __restrict__ out)     // [solution (T*B*3) | diff (T*B*3)]
{
    __shared__ __align__(16) float    sMeF[T_N];      // fp32 me
    __shared__ __align__(16) _Float16 sMeH[T_N];      // fp16 me (dot operand A)
    __shared__ __align__(16) _Float16 sIhR[8 * SIH];  // 8 shifted fp16 I-history rows
    __shared__ __align__(16) float    P[2][64][8];    // [parity][lane][wave] (slot 7 = 0)

    const int b   = blockIdx.x;
    const int tid = threadIdx.x;
    const int wid = tid >> 6;
    const int L   = tid & 63;

    // per-lane dot-geometry constants (chunk-invariant)
    const int f    = (-L) & 7;            // misalignment of lane L's me window
    const int R8   = L + f;               // L rounded up to multiple of 8
    const int row  = L & 7;               // I-history row for this lane
    const int iofs = row * SIH + (f ? 0 : 8);

    // zero the row front-pads (slots representing I[<0])
    if (tid < 64) sIhR[(tid >> 3) * SIH + (tid & 7)] = (_Float16)0.0f;
    // zero the unused P slot 7 for both parities
    if (tid < 128) P[tid >> 6][tid & 63][7] = 0.0f;

    // ---- Phase A: me MLP (2 values/thread) ----
#pragma unroll
    for (int v = 0; v < 2; ++v) {
        const int mi = tid + v * 512;
        const float x = t[mi];

        float h1[H_N], h2[H_N];
#pragma unroll
        for (int k = 0; k < H_N; ++k) h1[k] = fast_tanh(fmaf(x, w1[k], b1[k]));

#pragma unroll 4
        for (int k = 0; k < H_N; ++k) {
            float a = b2[k];
#pragma unroll
            for (int j = 0; j < H_N; ++j) a = fmaf(h1[j], w2[j * H_N + k], a);
            h2[k] = fast_tanh(a);
        }

        float a4 = b4[0];
#pragma unroll 4
        for (int k = 0; k < H_N; ++k) {
            float a = b3[k];
#pragma unroll
            for (int j = 0; j < H_N; ++j) a = fmaf(h2[j], w3[j * H_N + k], a);
            a4 = fmaf(fast_tanh(a), w4[k], a4);
        }

        const float meval = fast_sigmoid(a4);
        sMeF[mi] = meval;
        sMeH[mi] = (_Float16)meval;
    }

    // ---- scalars / state ----
    const float dt    = t[0] - t[1];
    const float beta  = beta_p[0];
    const float gma   = gamma_p[0];
    const float invdt = 1.0f / dt;
    const float dt2   = dt * dt;

    const float S0 = y[b * 3 + 0];
    const float I0 = y[b * 3 + 1];
    const float R0 = y[b * 3 + 2];
    const float TOT = S0 + I0 + R0;     // SIR total conserved

    // publish I[0] into all 8 rows
    if (tid < 8) sIhR[tid * SIH + 8 - tid] = (_Float16)I0;

    float* __restrict__ diff = out + (size_t)T_N * B_N * 3;
    if (tid < 3) diff[((size_t)(T_N - 1) * B_N + b) * 3 + tid] = 0.0f;

    __syncthreads();   // sMeF/sMeH/pads/I0/P-slot7 visible

    // fixup me weights (chunk-invariant, UNSCALED — applied to raw P sums)
    float mf[7];
#pragma unroll
    for (int d = 1; d <= 7; ++d) mf[d - 1] = sMeF[T_N - 64 - L - d];

    const float dtb   = dt * beta;
    const float ndtb  = -dtb;
    const float c1    = fmaf(-dt, gma, 1.0f);     // 1 - dt*gamma
    const float meT1s = dt2 * sMeF[T_N - 1];      // dt^2 * me[T-1]

    float S = S0, I = I0, oS = S0, oI = I0;
    float acc_cur = 0.0f, acc_nxt = 0.0f, pre = 0.0f;
    float carryS = S0, carryI = I0;

    // register me-tables (dt^2-scaled): 128 NAMED scalars
#define TBLDECL(k) float rm_##k, rn_##k;
    REP64(TBLDECL)
#undef TBLDECL
    if (wid == 0) {
#define TBLINIT(k)                                                          \
        rm_##k = (((k) < L) ? sMeF[T_N - L + (k)] : 0.0f) * dt2;            \
        rn_##k = dt2 * sMeF[T_N - 64 - L + (k)];
        REP64(TBLINIT)
#undef TBLINIT
#define TBLPIN(k) asm volatile("" : "+v"(rm_##k), "+v"(rn_##k));
        REP64(TBLPIN)
#undef TBLPIN
        // R5: raise wave0's scheduler priority for the whole serial phase.
        // Role-split (T5): one serial VALU wave vs 7 LDS-heavy dot waves;
        // round-robin co-issue with the SIMD-sharing dot wave otherwise
        // steals issue slots from the critical chain.
        __builtin_amdgcn_s_setprio(3);
    }

    // serial step M_: entering (S,I) = y_{64c+M_-1}; produces y_{64c+M_}.
    // pre was read BEFORE step (M_-1)'s fold -> patch with meT1s*I (distance-1).
#define STEPB(M_, FIRST_)                                               \
    {                                                                   \
        const float sum = (FIRST_) ? pre : fmaf(meT1s, I, pre);         \
        float pnx = pre;                                                \
        if ((M_) < 63) pnx = rdlane_i(acc_cur, (M_) + 1);               \
        const float a  = fmaf(dtb, S, c1);                              \
        const float bb = fmaf(ndtb, I, 1.0f);                           \
        S = fmaf(bb, S, sum);                                           \
        I = I * a;                                                      \
        const bool cap = (L == (M_));                                   \
        oS = cap ? S : oS;                                              \
        oI = cap ? I : oI;                                              \
        acc_cur = fmaf(rm_##M_, I, acc_cur);                            \
        acc_nxt = fmaf(rn_##M_, I, acc_nxt);                            \
        pre = pnx;                                                      \
    }
#define STEP_GE1(M_) if ((M_) >= 1) STEPB(M_, false)
#define STEP_GE2(M_) if ((M_) >= 2) STEPB(M_, false)

    for (int c = 0; c < 16; ++c) {
        if (wid == 0) {
            if (c == 0) {
                // fold initial I0 (tau=0 term); lane0's rm_0 is the 0 pad
                acc_cur = rm_0 * I;
                acc_nxt = rn_0 * I;
                pre = rdlane_i(acc_cur, 1);
                STEPB(1, true)
                REP64(STEP_GE2)
            } else {
                // chunk-head merge: 2x ds_read_b128 + 7 adds (P transposed)
                const float4 pa = *(const float4*)&P[c & 1][L][0];
                const float4 pb = *(const float4*)&P[c & 1][L][4];
                const float ps = ((pa.x + pa.y) + (pa.z + pa.w)) +
                                 ((pb.x + pb.y) + (pb.z + pb.w));   // slot7 = 0
                acc_cur = fmaf(dt2, ps, acc_nxt);  // scale raw P sums
                acc_nxt = 0.0f;
                pre = rdlane_i(acc_cur, 0);
                STEPB(0, true)
                REP64(STEP_GE1)
            }

            // ---- chunk epilogue (wave 0) ----
            const int j = 64 * c + L;
            const _Float16 hI = (_Float16)oI;
#pragma unroll
            for (int r = 0; r < 8; ++r) sIhR[r * SIH + 8 + (j - r)] = hI;

            const float oR = TOT - oS - oI;
            const size_t so = ((size_t)j * B_N + b) * 3;
            out[so + 0] = oS;
            out[so + 1] = oI;
            out[so + 2] = oR;

            float sm1 = __shfl_up(oS, 1);
            float im1 = __shfl_up(oI, 1);
            if (L == 0) { sm1 = carryS; im1 = carryI; }
            if (j > 0) {
                const float d0 = (oS - sm1) * invdt;
                const float d1 = (oI - im1) * invdt;
                const float d2 = -d0 - d1;
                const size_t dofs = ((size_t)(j - 1) * B_N + b) * 3;
                diff[dofs + 0] = d0;
                diff[dofs + 1] = d1;
                diff[dofs + 2] = d2;
            }
            carryS = rdlane_i(oS, 63);
            carryI = rdlane_i(oI, 63);
        } else if (c < 15) {
            // history dot for chunk c+1 over tau < 64c (R5 layout, unchanged)
            const int w    = wid - 1;
            const int G    = 8 * c;
            const int idx0 = (T_N - 64 * (c + 1)) - R8;
            float p0 = 0.0f, p1 = 0.0f;
            int s = w;
            for (; s + NDW < G; s += 2 * NDW) {
                const h8_t mv0 = *(const h8_t*)&sMeH[idx0 + 8 * s];
                const h8_t iv0 = *(const h8_t*)&sIhR[iofs + 8 * s];
                const h8_t mv1 = *(const h8_t*)&sMeH[idx0 + 8 * (s + NDW)];
                const h8_t iv1 = *(const h8_t*)&sIhR[iofs + 8 * (s + NDW)];
                DOT8(p0, mv0, iv0)
                DOT8(p1, mv1, iv1)
            }
            if (s < G) {
                const h8_t mv0 = *(const h8_t*)&sMeH[idx0 + 8 * s];
                const h8_t iv0 = *(const h8_t*)&sIhR[iofs + 8 * s];
                DOT8(p0, mv0, iv0)
            }
            float p = p0 + p1;
            if (w == 0) {
                // tail fixup: tau = 64c - d, d = 1..f (raw, scaled at merge)
#pragma unroll
                for (int d = 1; d <= 7; ++d) {
                    const float ih = (float)sIhR[8 + 64 * c - d];   // row 0
                    if (d <= f) p = fmaf(mf[d - 1], ih, p);
                }
            }
            P[(c + 1) & 1][L][w] = p;
        }
        __syncthreads();
    }
#undef STEPB
#undef STEP_GE1
#undef STEP_GE2
}

// ---------------------------------------------------------------------------
// Launcher
// ---------------------------------------------------------------------------
extern "C" void kernel_launch(void* const* d_in, const int* in_sizes, int n_in,
                              void* d_out, int out_size, void* d_ws, size_t ws_size,
                              hipStream_t stream) {
    const float* t     = (const float*)d_in[0];
    const float* y     = (const float*)d_in[1];
    const float* w1    = (const float*)d_in[2];
    const float* b1    = (const float*)d_in[3];
    const float* w2    = (const float*)d_in[4];
    const float* b2    = (const float*)d_in[5];
    const float* w3    = (const float*)d_in[6];
    const float* b3    = (const float*)d_in[7];
    const float* w4    = (const float*)d_in[8];
    const float* b4    = (const float*)d_in[9];
    const float* beta  = (const float*)d_in[10];
    const float* gamma = (const float*)d_in[11];

    scan_kernel<<<B_N, 512, 0, stream>>>(t, y, w1, b1, w2, b2, w3, b3, w4, b4,
                                         beta, gamma, (float*)d_out);
}

// Round 6
// 114.199 us; speedup vs baseline: 1.1661x; 1.0450x over previous
//
#include <hip/hip_runtime.h>

// Problem constants: T=1024, B=256, H=20
#define T_N 1024
#define B_N 256
#define H_N 20
#define NW  8            // waves per block
#define NDW (NW - 1)     // dot waves
#define SIH 1096         // I-history row stride in HALVES (conflict-free layout, see R5)

typedef _Float16 h8_t __attribute__((ext_vector_type(8)));

#if __has_builtin(__builtin_amdgcn_fdot2)
#define DOT8(acc, mv, iv)                                                           \
    acc = __builtin_amdgcn_fdot2(__builtin_shufflevector(mv, mv, 0, 1),             \
                                 __builtin_shufflevector(iv, iv, 0, 1), acc, false);\
    acc = __builtin_amdgcn_fdot2(__builtin_shufflevector(mv, mv, 2, 3),             \
                                 __builtin_shufflevector(iv, iv, 2, 3), acc, false);\
    acc = __builtin_amdgcn_fdot2(__builtin_shufflevector(mv, mv, 4, 5),             \
                                 __builtin_shufflevector(iv, iv, 4, 5), acc, false);\
    acc = __builtin_amdgcn_fdot2(__builtin_shufflevector(mv, mv, 6, 7),             \
                                 __builtin_shufflevector(iv, iv, 6, 7), acc, false);
#else
#define DOT8(acc, mv, iv)                                                           \
    _Pragma("unroll")                                                               \
    for (int _k = 0; _k < 8; ++_k) acc = fmaf((float)mv[_k], (float)iv[_k], acc);
#endif

__device__ __forceinline__ float rdlane_i(float v, int lane) {
    return __uint_as_float((unsigned)__builtin_amdgcn_readlane((int)__float_as_uint(v), lane));
}
__device__ __forceinline__ float fast_tanh(float x) {
    const float e = __expf(2.0f * x);
    return fmaf(-2.0f, __builtin_amdgcn_rcpf(e + 1.0f), 1.0f);
}
__device__ __forceinline__ float fast_sigmoid(float x) {
    return __builtin_amdgcn_rcpf(1.0f + __expf(-x));
}

// explicit literal-token repetition (tokens must be plain literals for ##)
#define REP64(F) \
    F(0) F(1) F(2) F(3) F(4) F(5) F(6) F(7) F(8) F(9) F(10) F(11) F(12) F(13) \
    F(14) F(15) F(16) F(17) F(18) F(19) F(20) F(21) F(22) F(23) F(24) F(25)   \
    F(26) F(27) F(28) F(29) F(30) F(31) F(32) F(33) F(34) F(35) F(36) F(37)   \
    F(38) F(39) F(40) F(41) F(42) F(43) F(44) F(45) F(46) F(47) F(48) F(49)   \
    F(50) F(51) F(52) F(53) F(54) F(55) F(56) F(57) F(58) F(59) F(60) F(61)   \
    F(62) F(63)

// ---------------------------------------------------------------------------
// R6: split the me-MLP into its own tiny kernel. Evidence: marginal-cost fit
// across R2-R5 (R3: +11 ops/step -> +11us; R5: -3 ops/step -> ~0) implies
// the serial chain is ISSUE-bound at ~2.2cy/op (~10-15us total) and the
// remaining ~35us is Phase A: the MLP's ~1600 per-thread weight loads,
// REPLICATED 256x (every block computes the identical me[1024]).
// Kernel 1 computes me once -> d_ws (fp32 + fp16, 6KB). Kernel 2 stages it
// from L2 and runs Phase B only. Also: P split into PA/PB[2][64][4] so the
// chunk-head merge reads are consecutive-per-lane b128 (conflict-free;
// removes R5's 414K bank conflicts).
// ---------------------------------------------------------------------------
__global__ __launch_bounds__(512, 1) void me_kernel(
    const float* __restrict__ t,
    const float* __restrict__ w1, const float* __restrict__ b1,
    const float* __restrict__ w2, const float* __restrict__ b2,
    const float* __restrict__ w3, const float* __restrict__ b3,
    const float* __restrict__ w4, const float* __restrict__ b4,
    float* __restrict__ me_f,        // [1024] fp32
    _Float16* __restrict__ me_h)     // [1024] fp16
{
    const int gid = blockIdx.x * 512 + threadIdx.x;   // 2 blocks x 512 = 1024
    const float x = t[gid];

    float h1[H_N], h2[H_N];
#pragma unroll
    for (int k = 0; k < H_N; ++k) h1[k] = fast_tanh(fmaf(x, w1[k], b1[k]));

#pragma unroll 4
    for (int k = 0; k < H_N; ++k) {
        float a = b2[k];
#pragma unroll
        for (int j = 0; j < H_N; ++j) a = fmaf(h1[j], w2[j * H_N + k], a);
        h2[k] = fast_tanh(a);
    }

    float a4 = b4[0];
#pragma unroll 4
    for (int k = 0; k < H_N; ++k) {
        float a = b3[k];
#pragma unroll
        for (int j = 0; j < H_N; ++j) a = fmaf(h2[j], w3[j * H_N + k], a);
        a4 = fmaf(fast_tanh(a), w4[k], a4);
    }

    const float meval = fast_sigmoid(a4);
    me_f[gid] = meval;
    me_h[gid] = (_Float16)meval;
}

__global__ __launch_bounds__(512, 1) void scan_kernel(
    const float* __restrict__ me_f,
    const _Float16* __restrict__ me_h,
    const float* __restrict__ t,
    const float* __restrict__ y,
    const float* __restrict__ beta_p,
    const float* __restrict__ gamma_p,
    float* __restrict__ out)     // [solution (T*B*3) | diff (T*B*3)]
{
    __shared__ __align__(16) float    sMeF[T_N];      // fp32 me
    __shared__ __align__(16) _Float16 sMeH[T_N];      // fp16 me (dot operand A)
    __shared__ __align__(16) _Float16 sIhR[8 * SIH];  // 8 shifted fp16 I-history rows
    __shared__ __align__(16) float    PA[2][64][4];   // dot partials, waves 1-4
    __shared__ __align__(16) float    PB[2][64][4];   // dot partials, waves 5-7 (+zero slot)

    const int b   = blockIdx.x;
    const int tid = threadIdx.x;
    const int wid = tid >> 6;
    const int L   = tid & 63;

    // per-lane dot-geometry constants (chunk-invariant)
    const int f    = (-L) & 7;            // misalignment of lane L's me window
    const int R8   = L + f;               // L rounded up to multiple of 8
    const int row  = L & 7;               // I-history row for this lane
    const int iofs = row * SIH + (f ? 0 : 8);

    // zero the row front-pads (slots representing I[<0])
    if (tid < 64) sIhR[(tid >> 3) * SIH + (tid & 7)] = (_Float16)0.0f;
    // zero the unused PB slot 3 for both parities
    if (tid < 128) PB[tid >> 6][tid & 63][3] = 0.0f;

    // ---- stage me from global (computed by me_kernel) ----
#pragma unroll
    for (int v = 0; v < 2; ++v) {
        const int mi = tid + v * 512;
        sMeF[mi] = me_f[mi];
        sMeH[mi] = me_h[mi];
    }

    // ---- scalars / state ----
    const float dt    = t[0] - t[1];
    const float beta  = beta_p[0];
    const float gma   = gamma_p[0];
    const float invdt = 1.0f / dt;
    const float dt2   = dt * dt;

    const float S0 = y[b * 3 + 0];
    const float I0 = y[b * 3 + 1];
    const float R0 = y[b * 3 + 2];
    const float TOT = S0 + I0 + R0;     // SIR total conserved

    // publish I[0] into all 8 rows
    if (tid < 8) sIhR[tid * SIH + 8 - tid] = (_Float16)I0;

    float* __restrict__ diff = out + (size_t)T_N * B_N * 3;
    if (tid < 3) diff[((size_t)(T_N - 1) * B_N + b) * 3 + tid] = 0.0f;

    __syncthreads();   // sMeF/sMeH/pads/I0/PB-slot3 visible

    // fixup me weights (chunk-invariant, UNSCALED — applied to raw P sums)
    float mf[7];
#pragma unroll
    for (int d = 1; d <= 7; ++d) mf[d - 1] = sMeF[T_N - 64 - L - d];

    const float dtb   = dt * beta;
    const float ndtb  = -dtb;
    const float c1    = fmaf(-dt, gma, 1.0f);     // 1 - dt*gamma
    const float meT1s = dt2 * sMeF[T_N - 1];      // dt^2 * me[T-1]

    float S = S0, I = I0, oS = S0, oI = I0;
    float acc_cur = 0.0f, acc_nxt = 0.0f, pre = 0.0f;
    float carryS = S0, carryI = I0;

    // register me-tables (dt^2-scaled): 128 NAMED scalars
#define TBLDECL(k) float rm_##k, rn_##k;
    REP64(TBLDECL)
#undef TBLDECL
    if (wid == 0) {
#define TBLINIT(k)                                                          \
        rm_##k = (((k) < L) ? sMeF[T_N - L + (k)] : 0.0f) * dt2;            \
        rn_##k = dt2 * sMeF[T_N - 64 - L + (k)];
        REP64(TBLINIT)
#undef TBLINIT
#define TBLPIN(k) asm volatile("" : "+v"(rm_##k), "+v"(rn_##k));
        REP64(TBLPIN)
#undef TBLPIN
        // wave0 priority: serial VALU wave vs 7 LDS-heavy dot waves (T5)
        __builtin_amdgcn_s_setprio(3);
    }

    // serial step M_: entering (S,I) = y_{64c+M_-1}; produces y_{64c+M_}.
    // pre was read BEFORE step (M_-1)'s fold -> patch with meT1s*I (distance-1).
#define STEPB(M_, FIRST_)                                               \
    {                                                                   \
        const float sum = (FIRST_) ? pre : fmaf(meT1s, I, pre);         \
        float pnx = pre;                                                \
        if ((M_) < 63) pnx = rdlane_i(acc_cur, (M_) + 1);               \
        const float a  = fmaf(dtb, S, c1);                              \
        const float bb = fmaf(ndtb, I, 1.0f);                           \
        S = fmaf(bb, S, sum);                                           \
        I = I * a;                                                      \
        const bool cap = (L == (M_));                                   \
        oS = cap ? S : oS;                                              \
        oI = cap ? I : oI;                                              \
        acc_cur = fmaf(rm_##M_, I, acc_cur);                            \
        acc_nxt = fmaf(rn_##M_, I, acc_nxt);                            \
        pre = pnx;                                                      \
    }
#define STEP_GE1(M_) if ((M_) >= 1) STEPB(M_, false)
#define STEP_GE2(M_) if ((M_) >= 2) STEPB(M_, false)

    for (int c = 0; c < 16; ++c) {
        if (wid == 0) {
            if (c == 0) {
                // fold initial I0 (tau=0 term); lane0's rm_0 is the 0 pad
                acc_cur = rm_0 * I;
                acc_nxt = rn_0 * I;
                pre = rdlane_i(acc_cur, 1);
                STEPB(1, true)
                REP64(STEP_GE2)
            } else {
                // chunk-head merge: 2x consecutive-per-lane ds_read_b128
                const float4 pa = *(const float4*)&PA[c & 1][L][0];
                const float4 pb = *(const float4*)&PB[c & 1][L][0];
                const float ps = ((pa.x + pa.y) + (pa.z + pa.w)) +
                                 ((pb.x + pb.y) + (pb.z + pb.w));   // PB slot3 = 0
                acc_cur = fmaf(dt2, ps, acc_nxt);  // scale raw P sums
                acc_nxt = 0.0f;
                pre = rdlane_i(acc_cur, 0);
                STEPB(0, true)
                REP64(STEP_GE1)
            }

            // ---- chunk epilogue (wave 0) ----
            const int j = 64 * c + L;
            const _Float16 hI = (_Float16)oI;
#pragma unroll
            for (int r = 0; r < 8; ++r) sIhR[r * SIH + 8 + (j - r)] = hI;

            const float oR = TOT - oS - oI;
            const size_t so = ((size_t)j * B_N + b) * 3;
            out[so + 0] = oS;
            out[so + 1] = oI;
            out[so + 2] = oR;

            float sm1 = __shfl_up(oS, 1);
            float im1 = __shfl_up(oI, 1);
            if (L == 0) { sm1 = carryS; im1 = carryI; }
            if (j > 0) {
                const float d0 = (oS - sm1) * invdt;
                const float d1 = (oI - im1) * invdt;
                const float d2 = -d0 - d1;
                const size_t dofs = ((size_t)(j - 1) * B_N + b) * 3;
                diff[dofs + 0] = d0;
                diff[dofs + 1] = d1;
                diff[dofs + 2] = d2;
            }
            carryS = rdlane_i(oS, 63);
            carryI = rdlane_i(oI, 63);
        } else if (c < 15) {
            // history dot for chunk c+1 over tau < 64c (R5 layout, unchanged)
            const int w    = wid - 1;
            const int G    = 8 * c;
            const int idx0 = (T_N - 64 * (c + 1)) - R8;
            float p0 = 0.0f, p1 = 0.0f;
            int s = w;
            for (; s + NDW < G; s += 2 * NDW) {
                const h8_t mv0 = *(const h8_t*)&sMeH[idx0 + 8 * s];
                const h8_t iv0 = *(const h8_t*)&sIhR[iofs + 8 * s];
                const h8_t mv1 = *(const h8_t*)&sMeH[idx0 + 8 * (s + NDW)];
                const h8_t iv1 = *(const h8_t*)&sIhR[iofs + 8 * (s + NDW)];
                DOT8(p0, mv0, iv0)
                DOT8(p1, mv1, iv1)
            }
            if (s < G) {
                const h8_t mv0 = *(const h8_t*)&sMeH[idx0 + 8 * s];
                const h8_t iv0 = *(const h8_t*)&sIhR[iofs + 8 * s];
                DOT8(p0, mv0, iv0)
            }
            float p = p0 + p1;
            if (w == 0) {
                // tail fixup: tau = 64c - d, d = 1..f (raw, scaled at merge)
#pragma unroll
                for (int d = 1; d <= 7; ++d) {
                    const float ih = (float)sIhR[8 + 64 * c - d];   // row 0
                    if (d <= f) p = fmaf(mf[d - 1], ih, p);
                }
            }
            if (w < 4) PA[(c + 1) & 1][L][w] = p;
            else       PB[(c + 1) & 1][L][w - 4] = p;
        }
        __syncthreads();
    }
#undef STEPB
#undef STEP_GE1
#undef STEP_GE2
}

// ---------------------------------------------------------------------------
// Launcher: me_kernel (2 blocks) then scan_kernel (256 blocks), same stream.
// d_ws layout: [0,4096) fp32 me; [4096,6144) fp16 me.
// ---------------------------------------------------------------------------
extern "C" void kernel_launch(void* const* d_in, const int* in_sizes, int n_in,
                              void* d_out, int out_size, void* d_ws, size_t ws_size,
                              hipStream_t stream) {
    const float* t     = (const float*)d_in[0];
    const float* y     = (const float*)d_in[1];
    const float* w1    = (const float*)d_in[2];
    const float* b1    = (const float*)d_in[3];
    const float* w2    = (const float*)d_in[4];
    const float* b2    = (const float*)d_in[5];
    const float* w3    = (const float*)d_in[6];
    const float* b3    = (const float*)d_in[7];
    const float* w4    = (const float*)d_in[8];
    const float* b4    = (const float*)d_in[9];
    const float* beta  = (const float*)d_in[10];
    const float* gamma = (const float*)d_in[11];

    float*    me_f = (float*)d_ws;
    _Float16* me_h = (_Float16*)((char*)d_ws + 4096);

    me_kernel<<<2, 512, 0, stream>>>(t, w1, b1, w2, b2, w3, b3, w4, b4, me_f, me_h);
    scan_kernel<<<B_N, 512, 0, stream>>>(me_f, me_h, t, y, beta, gamma, (float*)d_out);
}